// Round 22
// baseline (985.653 us; speedup 1.0000x reference)
//
#include <hip/hip_runtime.h>
#include <cstddef>
#include <cstdint>
#include <math.h>

typedef __bf16 bf16_t;
typedef __bf16 bf16x8 __attribute__((ext_vector_type(8)));
typedef float  f32x4  __attribute__((ext_vector_type(4)));

#define MFMA16(A,B,C) __builtin_amdgcn_mfma_f32_16x16x32_bf16((A),(B),(C),0,0,0)
#define QFIX_CAP 262144

// B=2, L=2048, D=1024, H=16, Dh=64.
// r22: ALL GEMMs single-pass bf16 (0.25 KB staged/MFMA, m97 intensity).
// Q floors stay bit-exact: flag window widened to 4e-3 (t-units) = 3.2x the
// 1-pass GEMM's max error (1.24e-3); flagged elements recomputed with the
// r11-verified KC=512 f32 chain. Out-proj drops o_lo (adds ~0.002 smooth err).

__device__ __forceinline__ void gload16(const bf16_t* g, bf16_t* l)
{
    auto* lp = reinterpret_cast<__attribute__((address_space(3))) uint32_t*>(
                   reinterpret_cast<uintptr_t>(l));
    const auto* gp = reinterpret_cast<const __attribute__((address_space(1))) uint32_t*>(
                   reinterpret_cast<uintptr_t>(g));
    __builtin_amdgcn_global_load_lds(gp, lp, 16, 0, 0);
}

// ---------------------------------------------------------------------------
__global__ void k_conv_x(const float* __restrict__ x, bf16_t* __restrict__ xhi)
{
    int i = blockIdx.x * blockDim.x + threadIdx.x;
    float4 v = reinterpret_cast<const float4*>(x)[i];
    bf16_t* ph = xhi + 4*(size_t)i;
    ph[0]=(bf16_t)v.x; ph[1]=(bf16_t)v.y; ph[2]=(bf16_t)v.z; ph[3]=(bf16_t)v.w;
}

// W f32 [k][n] (1024x1024) -> T[n][k] bf16
__global__ void k_transpose(const float* __restrict__ W, bf16_t* __restrict__ T)
{
    __shared__ float tile[32][33];
    int t = threadIdx.x, r = t >> 5, c = t & 31;
    int k0 = blockIdx.y * 32, n0 = blockIdx.x * 32;
#pragma unroll
    for (int i = 0; i < 4; i++)
        tile[r + i*8][c] = W[(size_t)(k0 + r + i*8) * 1024 + n0 + c];
    __syncthreads();
#pragma unroll
    for (int i = 0; i < 4; i++) {
        int nr = r + i*8;
        T[(size_t)(n0 + nr) * 1024 + k0 + c] = (bf16_t)tile[c][nr];
    }
}

// ---------------------------------------------------------------------------
// Single-pass bf16 MFMA GEMM, depth-2 prefetch, 3 LDS buffers, XCD-local B.
// MODE 0 (QKV): 128x128 tile, N=3072. Epilogue: Q floor+flag(4e-3) / K / V^T.
// MODE 1 (out-proj): 64x128 tile, N=1024 -> f32 d_out + bo.
template<int MODE>
__launch_bounds__(256)
__global__ void k_gemm3(const bf16_t* __restrict__ A, const bf16_t* __restrict__ Bt,
                        const float* __restrict__ b0, const float* __restrict__ b1,
                        const float* __restrict__ b2,
                        bf16_t* __restrict__ qout, int2* __restrict__ qwl,
                        int* __restrict__ qcnt,
                        bf16_t* __restrict__ kho, bf16_t* __restrict__ vho,
                        float* __restrict__ fout)
{
    constexpr int BM = (MODE == 0) ? 128 : 64;
    __shared__ bf16_t As[3][BM*32]  __attribute__((aligned(16)));
    __shared__ bf16_t Bs[3][128*32] __attribute__((aligned(16)));

    const int bid = blockIdx.x;
    const int xcd = bid & 7;
    const int i   = bid >> 3;
    int n0, m0;
    if constexpr (MODE == 0) {
        // 24 n-tiles: each XCD owns 3 (768KB B-slice, L2-resident); m-inner
        n0 = (xcd * 3 + (i % 3)) * 128;
        m0 = (i / 3) * 128;
    } else {
        n0 = xcd * 128;
        m0 = i * 64;
    }

    const int tid = threadIdx.x;
    const int wid = tid >> 6, lane = tid & 63, lane16 = lane & 15, lg = lane >> 4;
    constexpr int WM = (MODE == 0) ? 64 : 32;    // per-wave m extent
    const int wm = (wid >> 1) * WM, wn = (wid & 1) * 64;
    constexpr int MI = (MODE == 0) ? 4 : 2;      // m-frags per wave

    f32x4 acc[MI][4] = {};

    // gloads/thread/stage: MODE0: A 2 + B 2 = 4;  MODE1: A 1 + B 2 = 3.
    auto STAGE = [&](int buf, int kt) {
        const int k0 = kt * 32;
#pragma unroll
        for (int i2 = 0; i2 < BM/64; i2++) {
            const int c = tid + i2*256;
            const int row = c >> 2, col = (c & 3) * 8;
            gload16(&A[(size_t)(m0 + row) * 1024 + k0 + col], &As[buf][c*8]);
        }
#pragma unroll
        for (int i2 = 0; i2 < 2; i2++) {
            const int c = tid + i2*256;
            const int row = c >> 2, col = (c & 3) * 8;
            gload16(&Bt[(size_t)(n0 + row) * 1024 + k0 + col], &Bs[buf][c*8]);
        }
    };

    STAGE(0, 0);
    STAGE(1, 1);
    for (int kt = 0; kt < 32; ++kt) {
        const int cur = kt % 3;
        if (kt < 31) {
            if constexpr (MODE == 0) { asm volatile("s_waitcnt vmcnt(4)" ::: "memory"); }
            else                     { asm volatile("s_waitcnt vmcnt(3)" ::: "memory"); }
        } else asm volatile("s_waitcnt vmcnt(0)" ::: "memory");
        __builtin_amdgcn_s_barrier();

        bf16x8 a[MI], b[4];
#pragma unroll
        for (int ii = 0; ii < MI; ii++)
            a[ii] = *reinterpret_cast<const bf16x8*>(&As[cur][(wm + ii*16 + lane16)*32 + lg*8]);
#pragma unroll
        for (int j = 0; j < 4; j++)
            b[j] = *reinterpret_cast<const bf16x8*>(&Bs[cur][(wn + j*16 + lane16)*32 + lg*8]);
#pragma unroll
        for (int ii = 0; ii < MI; ii++)
#pragma unroll
            for (int j = 0; j < 4; j++)
                acc[ii][j] = MFMA16(a[ii], b[j], acc[ii][j]);

        if (kt + 2 < 32) STAGE((kt + 2) % 3, kt + 2);
    }

#pragma unroll
    for (int j = 0; j < 4; j++) {
        const int n = n0 + wn + j*16 + lane16;
#pragma unroll
        for (int ii = 0; ii < MI; ii++) {
#pragma unroll
            for (int r = 0; r < 4; r++) {
                const int m = m0 + wm + ii*16 + lg*4 + r;
                float v = acc[ii][j][r];
                if constexpr (MODE == 1) {
                    fout[(size_t)m*1024 + n] = v + b0[n];
                } else {
                    const int bb = m >> 11, l = m & 2047;
                    if (n < 1024) {                       // Q: floor + WIDE flag window
                        float vv = v + b0[n];
                        float t  = vv * 0.125f;
                        float fl = floorf(t);
                        float fr = t - fl;
                        if (fr < 4e-3f || fr > 0.996f) {  // covers 1-pass GEMM err (3.2x)
                            int idx = atomicAdd(qcnt, 1);
                            if (idx < QFIX_CAP) qwl[idx] = make_int2(m, n);
                        }
                        qout[(((size_t)(bb*16 + (n>>6)))*2048 + l)*64 + (n&63)] = (bf16_t)fl;
                    } else if (n < 2048) {                // K -> bf16 [B,H,L,Dh]
                        const int nk = n - 1024;
                        kho[(((size_t)(bb*16 + (nk>>6)))*2048 + l)*64 + (nk&63)] =
                            (bf16_t)(v + b1[nk]);
                    } else {                              // V -> bf16 [B,H,Dh,L]
                        const int nv = n - 2048;
                        vho[(((size_t)(bb*16 + (nv>>6)))*64 + (nv&63))*2048 + l] =
                            (bf16_t)(v + b2[nv]);
                    }
                }
            }
        }
    }
}

// ---------------------------------------------------------------------------
// Exact fixup (r11-verified arithmetic, bit-identical): recompute flagged q.
__launch_bounds__(256)
__global__ void k_qfix(const float* __restrict__ x, const float* __restrict__ Wq,
                       const float* __restrict__ bq, const int2* __restrict__ wl,
                       const int* __restrict__ count, bf16_t* __restrict__ qout)
{
    int i = blockIdx.x * 256 + threadIdx.x;
    int cnt = *count; if (cnt > QFIX_CAP) cnt = QFIX_CAP;
    if (i >= cnt) return;
    const int m = wl[i].x, n = wl[i].y;
    const float* xr = x + (size_t)m * 1024;
    float acc = 0.0f;
#pragma unroll 1
    for (int blk = 0; blk < 2; blk++) {
        float r = 0.0f;
        const int d0 = blk * 512;
#pragma unroll 8
        for (int d = d0; d < d0 + 512; d++)
            r = fmaf(xr[d], Wq[(size_t)d * 1024 + n], r);
        acc = __fadd_rn(acc, r);
    }
    float q = floorf(__fmul_rn(__fadd_rn(acc, bq[n]), 0.125f));
    qout[(((size_t)((m>>11)*16 + (n>>6)))*2048 + (m&2047))*64 + (n&63)] = (bf16_t)q;
}

// ---------------------------------------------------------------------------
// Flash attention, bf16 K/V/P. grid (L/64, B*H); 4 waves x 16 q-rows.
__launch_bounds__(256)
__global__ void k_attn(const bf16_t* __restrict__ qf,
                       const bf16_t* __restrict__ khi,
                       const bf16_t* __restrict__ vhiT,
                       bf16_t* __restrict__ ohi)
{
    __shared__ bf16_t Kh[64*72] __attribute__((aligned(16)));
    __shared__ bf16_t Vh[64*72] __attribute__((aligned(16)));
    __shared__ bf16_t Ph[4*16*72] __attribute__((aligned(16)));
    const int tid = threadIdx.x, wid = tid >> 6, lane = tid & 63;
    const int lane16 = lane & 15, lg = lane >> 4;
    const int qt = blockIdx.x, bh = blockIdx.y;
    const bf16_t* qb  = qf   + (size_t)bh * 2048 * 64;
    const bf16_t* khb = khi  + (size_t)bh * 2048 * 64;
    const bf16_t* vhb = vhiT + (size_t)bh * 64 * 2048;
    const int q0 = qt * 64;
    const int qrow16 = q0 + wid*16 + lane16;

    bf16x8 qfr0 = *reinterpret_cast<const bf16x8*>(&qb[(size_t)qrow16*64 + lg*8]);
    bf16x8 qfr1 = *reinterpret_cast<const bf16x8*>(&qb[(size_t)qrow16*64 + 32 + lg*8]);

    f32x4 acco[4] = {};
    float mrow[4] = {-1e30f, -1e30f, -1e30f, -1e30f};
    float lrow[4] = {0.f, 0.f, 0.f, 0.f};
    const float L2E = 1.44269504088896f;

    for (int t = 0; t <= qt; t++) {
        const int kv0 = t * 64;
#pragma unroll
        for (int i = 0; i < 2; i++) {
            int cc = tid + i*256, row = cc >> 3, col8 = (cc & 7) * 8;
            size_t go = (size_t)(kv0+row)*64 + col8;
            size_t gv = (size_t)row*2048 + kv0 + col8;
            *reinterpret_cast<bf16x8*>(&Kh[row*72 + col8]) = *reinterpret_cast<const bf16x8*>(&khb[go]);
            *reinterpret_cast<bf16x8*>(&Vh[row*72 + col8]) = *reinterpret_cast<const bf16x8*>(&vhb[gv]);
        }
        __syncthreads();

        f32x4 s[4] = {};
#pragma unroll
        for (int st = 0; st < 4; st++) {
            const int ro = (st*16 + lane16)*72;
            bf16x8 kh0 = *reinterpret_cast<const bf16x8*>(&Kh[ro + lg*8]);
            bf16x8 kh1 = *reinterpret_cast<const bf16x8*>(&Kh[ro + 32 + lg*8]);
            s[st] = MFMA16(qfr0, kh0, s[st]);
            s[st] = MFMA16(qfr1, kh1, s[st]);
        }
        if (t == qt) {
#pragma unroll
            for (int st = 0; st < 4; st++) {
                int key = kv0 + st*16 + lane16;
#pragma unroll
                for (int r = 0; r < 4; r++) {
                    int qr = q0 + wid*16 + lg*4 + r;
                    if (key > qr) s[st][r] = -1e30f;
                }
            }
        }
        float rmax[4];
#pragma unroll
        for (int r = 0; r < 4; r++)
            rmax[r] = fmaxf(fmaxf(s[0][r], s[1][r]), fmaxf(s[2][r], s[3][r]));
#pragma unroll
        for (int off = 1; off < 16; off <<= 1)
#pragma unroll
            for (int r = 0; r < 4; r++) rmax[r] = fmaxf(rmax[r], __shfl_xor(rmax[r], off));
        float scl[4];
#pragma unroll
        for (int r = 0; r < 4; r++) {
            float mn = fmaxf(mrow[r], rmax[r]);
            scl[r] = exp2f((mrow[r] - mn) * L2E);
            mrow[r] = mn;
        }
        float rs[4] = {0.f, 0.f, 0.f, 0.f};
#pragma unroll
        for (int st = 0; st < 4; st++) {
#pragma unroll
            for (int r = 0; r < 4; r++) {
                float p = exp2f((s[st][r] - mrow[r]) * L2E);
                rs[r] += p;
                Ph[wid*16*72 + (lg*4 + r)*72 + st*16 + lane16] = (bf16_t)p;
            }
        }
#pragma unroll
        for (int off = 1; off < 16; off <<= 1)
#pragma unroll
            for (int r = 0; r < 4; r++) rs[r] += __shfl_xor(rs[r], off);
#pragma unroll
        for (int r = 0; r < 4; r++) lrow[r] = lrow[r]*scl[r] + rs[r];
#pragma unroll
        for (int nf = 0; nf < 4; nf++)
#pragma unroll
            for (int r = 0; r < 4; r++) acco[nf][r] *= scl[r];

        __syncthreads();
#pragma unroll
        for (int ks = 0; ks < 2; ks++) {
            bf16x8 phf = *reinterpret_cast<const bf16x8*>(&Ph[wid*16*72 + lane16*72 + ks*32 + lg*8]);
#pragma unroll
            for (int nf = 0; nf < 4; nf++) {
                bf16x8 vh = *reinterpret_cast<const bf16x8*>(&Vh[(nf*16 + lane16)*72 + ks*32 + lg*8]);
                acco[nf] = MFMA16(phf, vh, acco[nf]);
            }
        }
        __syncthreads();
    }

    const int b = bh >> 4, h = bh & 15;
#pragma unroll
    for (int r = 0; r < 4; r++) {
        float inv = 1.0f / lrow[r];
        int qr = q0 + wid*16 + lg*4 + r;
        size_t base = ((size_t)(b*2048 + qr))*1024 + h*64;
#pragma unroll
        for (int nf = 0; nf < 4; nf++)
            ohi[base + nf*16 + lane16] = (bf16_t)(acco[nf][r] * inv);
    }
}

// ---------------------------------------------------------------------------
extern "C" void kernel_launch(void* const* d_in, const int* in_sizes, int n_in,
                              void* d_out, int out_size, void* d_ws, size_t ws_size,
                              hipStream_t stream)
{
    const float* x  = (const float*)d_in[0];
    const float* Wq = (const float*)d_in[1];
    const float* bq = (const float*)d_in[2];
    const float* Wk = (const float*)d_in[3];
    const float* bk = (const float*)d_in[4];
    const float* Wv = (const float*)d_in[5];
    const float* bv = (const float*)d_in[6];
    const float* Wo = (const float*)d_in[7];
    const float* bo = (const float*)d_in[8];

    char* ws = (char*)d_ws;
    const size_t MB = (size_t)1 << 20;
    bf16_t* xhi    = (bf16_t*)(ws +  0*MB);  // [4096][1024] 8MB
    bf16_t* WThi   = (bf16_t*)(ws +  8*MB);  // [3072][1024] 6MB (Wq|Wk|Wv ^T)
    bf16_t* WoThi  = (bf16_t*)(ws + 14*MB);  // 2MB
    bf16_t* qbuf   = (bf16_t*)(ws + 16*MB);  // [B,H,L,Dh] 8MB
    bf16_t* khibuf = (bf16_t*)(ws + 24*MB);  // 8MB
    bf16_t* vhiT   = (bf16_t*)(ws + 32*MB);  // [B,H,Dh,L] 8MB
    bf16_t* ohibuf = (bf16_t*)(ws + 40*MB);  // [4096][1024] 8MB
    int2*   qwl    = (int2*)  (ws + 48*MB);  // 2MB
    int*    qcnt   = (int*)   (ws + 50*MB);  // 4B

    hipMemsetAsync(qcnt, 0, 4, stream);
    k_conv_x<<<4096, 256, 0, stream>>>(x, xhi);
    dim3 tg(32, 32);
    k_transpose<<<tg, 256, 0, stream>>>(Wq, WThi);
    k_transpose<<<tg, 256, 0, stream>>>(Wk, WThi + (size_t)1024*1024);
    k_transpose<<<tg, 256, 0, stream>>>(Wv, WThi + (size_t)2048*1024);
    k_transpose<<<tg, 256, 0, stream>>>(Wo, WoThi);

    k_gemm3<0><<<768, 256, 0, stream>>>(xhi, WThi, bq, bk, bv,
                                        qbuf, qwl, qcnt, khibuf, vhiT, nullptr);
    k_qfix<<<1024, 256, 0, stream>>>(x, Wq, bq, qwl, qcnt, qbuf);
    k_attn<<<dim3(32, 32), 256, 0, stream>>>(qbuf, khibuf, vhiT, ohibuf);
    k_gemm3<1><<<512, 256, 0, stream>>>(ohibuf, WoThi, bo, nullptr, nullptr,
                                        nullptr, nullptr, nullptr,
                                        nullptr, nullptr, (float*)d_out);
}

// Round 23
// 374.820 us; speedup vs baseline: 2.6297x; 2.6297x over previous
//
#include <hip/hip_runtime.h>
#include <cstddef>
#include <cstdint>
#include <math.h>

typedef __bf16 bf16_t;
typedef __bf16 bf16x8 __attribute__((ext_vector_type(8)));
typedef float  f32x4  __attribute__((ext_vector_type(4)));

#define MFMA16(A,B,C) __builtin_amdgcn_mfma_f32_16x16x32_bf16((A),(B),(C),0,0,0)
#define QFIX_CAP 262144

// B=2, L=2048, D=1024, H=16, Dh=64.
// r23 = r22 + wave-aggregated flag append (1 atomic/wave instead of 1/element).
// r22's regression was ~107k serialized atomicAdd-with-return on one address
// (~450us) — also the hidden invariant tail in r14-r21. Flag SET unchanged;
// worklist order permuted (qfix is order-independent) -> absmax 0.0390625.

__device__ __forceinline__ void gload16(const bf16_t* g, bf16_t* l)
{
    auto* lp = reinterpret_cast<__attribute__((address_space(3))) uint32_t*>(
                   reinterpret_cast<uintptr_t>(l));
    const auto* gp = reinterpret_cast<const __attribute__((address_space(1))) uint32_t*>(
                   reinterpret_cast<uintptr_t>(g));
    __builtin_amdgcn_global_load_lds(gp, lp, 16, 0, 0);
}

// ---------------------------------------------------------------------------
__global__ void k_conv_x(const float* __restrict__ x, bf16_t* __restrict__ xhi)
{
    int i = blockIdx.x * blockDim.x + threadIdx.x;
    float4 v = reinterpret_cast<const float4*>(x)[i];
    bf16_t* ph = xhi + 4*(size_t)i;
    ph[0]=(bf16_t)v.x; ph[1]=(bf16_t)v.y; ph[2]=(bf16_t)v.z; ph[3]=(bf16_t)v.w;
}

// W f32 [k][n] (1024x1024) -> T[n][k] bf16
__global__ void k_transpose(const float* __restrict__ W, bf16_t* __restrict__ T)
{
    __shared__ float tile[32][33];
    int t = threadIdx.x, r = t >> 5, c = t & 31;
    int k0 = blockIdx.y * 32, n0 = blockIdx.x * 32;
#pragma unroll
    for (int i = 0; i < 4; i++)
        tile[r + i*8][c] = W[(size_t)(k0 + r + i*8) * 1024 + n0 + c];
    __syncthreads();
#pragma unroll
    for (int i = 0; i < 4; i++) {
        int nr = r + i*8;
        T[(size_t)(n0 + nr) * 1024 + k0 + c] = (bf16_t)tile[c][nr];
    }
}

// ---------------------------------------------------------------------------
// Single-pass bf16 MFMA GEMM, depth-2 prefetch, 3 LDS buffers, XCD-local B.
// MODE 0 (QKV): 128x128 tile, N=3072. Epilogue: Q floor+flag(4e-3) / K / V^T.
// MODE 1 (out-proj): 64x128 tile, N=1024 -> f32 d_out + bo.
template<int MODE>
__launch_bounds__(256)
__global__ void k_gemm3(const bf16_t* __restrict__ A, const bf16_t* __restrict__ Bt,
                        const float* __restrict__ b0, const float* __restrict__ b1,
                        const float* __restrict__ b2,
                        bf16_t* __restrict__ qout, int2* __restrict__ qwl,
                        int* __restrict__ qcnt,
                        bf16_t* __restrict__ kho, bf16_t* __restrict__ vho,
                        float* __restrict__ fout)
{
    constexpr int BM = (MODE == 0) ? 128 : 64;
    __shared__ bf16_t As[3][BM*32]  __attribute__((aligned(16)));
    __shared__ bf16_t Bs[3][128*32] __attribute__((aligned(16)));

    const int bid = blockIdx.x;
    const int xcd = bid & 7;
    const int i   = bid >> 3;
    int n0, m0;
    if constexpr (MODE == 0) {
        n0 = (xcd * 3 + (i % 3)) * 128;   // each XCD owns 3 n-tiles (L2-resident B)
        m0 = (i / 3) * 128;
    } else {
        n0 = xcd * 128;
        m0 = i * 64;
    }

    const int tid = threadIdx.x;
    const int wid = tid >> 6, lane = tid & 63, lane16 = lane & 15, lg = lane >> 4;
    constexpr int WM = (MODE == 0) ? 64 : 32;
    const int wm = (wid >> 1) * WM, wn = (wid & 1) * 64;
    constexpr int MI = (MODE == 0) ? 4 : 2;

    f32x4 acc[MI][4] = {};

    auto STAGE = [&](int buf, int kt) {
        const int k0 = kt * 32;
#pragma unroll
        for (int i2 = 0; i2 < BM/64; i2++) {
            const int c = tid + i2*256;
            const int row = c >> 2, col = (c & 3) * 8;
            gload16(&A[(size_t)(m0 + row) * 1024 + k0 + col], &As[buf][c*8]);
        }
#pragma unroll
        for (int i2 = 0; i2 < 2; i2++) {
            const int c = tid + i2*256;
            const int row = c >> 2, col = (c & 3) * 8;
            gload16(&Bt[(size_t)(n0 + row) * 1024 + k0 + col], &Bs[buf][c*8]);
        }
    };

    STAGE(0, 0);
    STAGE(1, 1);
    for (int kt = 0; kt < 32; ++kt) {
        const int cur = kt % 3;
        if (kt < 31) {
            if constexpr (MODE == 0) { asm volatile("s_waitcnt vmcnt(4)" ::: "memory"); }
            else                     { asm volatile("s_waitcnt vmcnt(3)" ::: "memory"); }
        } else asm volatile("s_waitcnt vmcnt(0)" ::: "memory");
        __builtin_amdgcn_s_barrier();

        bf16x8 a[MI], b[4];
#pragma unroll
        for (int ii = 0; ii < MI; ii++)
            a[ii] = *reinterpret_cast<const bf16x8*>(&As[cur][(wm + ii*16 + lane16)*32 + lg*8]);
#pragma unroll
        for (int j = 0; j < 4; j++)
            b[j] = *reinterpret_cast<const bf16x8*>(&Bs[cur][(wn + j*16 + lane16)*32 + lg*8]);
#pragma unroll
        for (int ii = 0; ii < MI; ii++)
#pragma unroll
            for (int j = 0; j < 4; j++)
                acc[ii][j] = MFMA16(a[ii], b[j], acc[ii][j]);

        if (kt + 2 < 32) STAGE((kt + 2) % 3, kt + 2);
    }

    if constexpr (MODE == 1) {
#pragma unroll
        for (int j = 0; j < 4; j++) {
            const int n = n0 + wn + j*16 + lane16;
#pragma unroll
            for (int ii = 0; ii < MI; ii++)
#pragma unroll
                for (int r = 0; r < 4; r++) {
                    const int m = m0 + wm + ii*16 + lg*4 + r;
                    fout[(size_t)m*1024 + n] = acc[ii][j][r] + b0[n];
                }
        }
    } else if (n0 >= 1024) {
        // K/V epilogue (no flags)
#pragma unroll
        for (int j = 0; j < 4; j++) {
            const int n = n0 + wn + j*16 + lane16;
#pragma unroll
            for (int ii = 0; ii < MI; ii++)
#pragma unroll
                for (int r = 0; r < 4; r++) {
                    const int m = m0 + wm + ii*16 + lg*4 + r;
                    const int bb = m >> 11, l = m & 2047;
                    float v = acc[ii][j][r];
                    if (n < 2048) {
                        const int nk = n - 1024;
                        kho[(((size_t)(bb*16 + (nk>>6)))*2048 + l)*64 + (nk&63)] =
                            (bf16_t)(v + b1[nk]);
                    } else {
                        const int nv = n - 2048;
                        vho[(((size_t)(bb*16 + (nv>>6)))*64 + (nv&63))*2048 + l] =
                            (bf16_t)(v + b2[nv]);
                    }
                }
        }
    } else {
        // Q epilogue: store floors + wave-aggregated flag append (1 atomic/wave)
        int cnt = 0;
#pragma unroll
        for (int j = 0; j < 4; j++) {
            const int n = n0 + wn + j*16 + lane16;
            const float bias = b0[n];
#pragma unroll
            for (int ii = 0; ii < MI; ii++)
#pragma unroll
                for (int r = 0; r < 4; r++) {
                    const int m = m0 + wm + ii*16 + lg*4 + r;
                    const int bb = m >> 11, l = m & 2047;
                    float t  = (acc[ii][j][r] + bias) * 0.125f;
                    float fl = floorf(t);
                    float fr = t - fl;
                    cnt += (fr < 4e-3f || fr > 0.996f) ? 1 : 0;
                    qout[(((size_t)(bb*16 + (n>>6)))*2048 + l)*64 + (n&63)] = (bf16_t)fl;
                }
        }
        // wave inclusive prefix-sum of cnt
        int pre = cnt;
#pragma unroll
        for (int off = 1; off < 64; off <<= 1) {
            int t2 = __shfl_up(pre, off);
            if (lane >= off) pre += t2;
        }
        int total = __shfl(pre, 63);
        int base = 0;
        if (lane == 63 && total > 0) base = atomicAdd(qcnt, total);
        base = __shfl(base, 63);
        int idx = base + pre - cnt;                 // exclusive offset
        // replay predicate (acc still in registers), write entries
#pragma unroll
        for (int j = 0; j < 4; j++) {
            const int n = n0 + wn + j*16 + lane16;
            const float bias = b0[n];
#pragma unroll
            for (int ii = 0; ii < MI; ii++)
#pragma unroll
                for (int r = 0; r < 4; r++) {
                    const int m = m0 + wm + ii*16 + lg*4 + r;
                    float t  = (acc[ii][j][r] + bias) * 0.125f;
                    float fr = t - floorf(t);
                    if (fr < 4e-3f || fr > 0.996f) {
                        if (idx < QFIX_CAP) qwl[idx] = make_int2(m, n);
                        idx++;
                    }
                }
        }
    }
}

// ---------------------------------------------------------------------------
// Exact fixup (r11-verified arithmetic, bit-identical): recompute flagged q.
__launch_bounds__(256)
__global__ void k_qfix(const float* __restrict__ x, const float* __restrict__ Wq,
                       const float* __restrict__ bq, const int2* __restrict__ wl,
                       const int* __restrict__ count, bf16_t* __restrict__ qout)
{
    int i = blockIdx.x * 256 + threadIdx.x;
    int cnt = *count; if (cnt > QFIX_CAP) cnt = QFIX_CAP;
    if (i >= cnt) return;
    const int m = wl[i].x, n = wl[i].y;
    const float* xr = x + (size_t)m * 1024;
    float acc = 0.0f;
#pragma unroll 1
    for (int blk = 0; blk < 2; blk++) {
        float r = 0.0f;
        const int d0 = blk * 512;
#pragma unroll 8
        for (int d = d0; d < d0 + 512; d++)
            r = fmaf(xr[d], Wq[(size_t)d * 1024 + n], r);
        acc = __fadd_rn(acc, r);
    }
    float q = floorf(__fmul_rn(__fadd_rn(acc, bq[n]), 0.125f));
    qout[(((size_t)((m>>11)*16 + (n>>6)))*2048 + (m&2047))*64 + (n&63)] = (bf16_t)q;
}

// ---------------------------------------------------------------------------
// Flash attention, bf16 K/V/P. grid (L/64, B*H); 4 waves x 16 q-rows.
__launch_bounds__(256)
__global__ void k_attn(const bf16_t* __restrict__ qf,
                       const bf16_t* __restrict__ khi,
                       const bf16_t* __restrict__ vhiT,
                       bf16_t* __restrict__ ohi)
{
    __shared__ bf16_t Kh[64*72] __attribute__((aligned(16)));
    __shared__ bf16_t Vh[64*72] __attribute__((aligned(16)));
    __shared__ bf16_t Ph[4*16*72] __attribute__((aligned(16)));
    const int tid = threadIdx.x, wid = tid >> 6, lane = tid & 63;
    const int lane16 = lane & 15, lg = lane >> 4;
    const int qt = blockIdx.x, bh = blockIdx.y;
    const bf16_t* qb  = qf   + (size_t)bh * 2048 * 64;
    const bf16_t* khb = khi  + (size_t)bh * 2048 * 64;
    const bf16_t* vhb = vhiT + (size_t)bh * 64 * 2048;
    const int q0 = qt * 64;
    const int qrow16 = q0 + wid*16 + lane16;

    bf16x8 qfr0 = *reinterpret_cast<const bf16x8*>(&qb[(size_t)qrow16*64 + lg*8]);
    bf16x8 qfr1 = *reinterpret_cast<const bf16x8*>(&qb[(size_t)qrow16*64 + 32 + lg*8]);

    f32x4 acco[4] = {};
    float mrow[4] = {-1e30f, -1e30f, -1e30f, -1e30f};
    float lrow[4] = {0.f, 0.f, 0.f, 0.f};
    const float L2E = 1.44269504088896f;

    for (int t = 0; t <= qt; t++) {
        const int kv0 = t * 64;
#pragma unroll
        for (int i = 0; i < 2; i++) {
            int cc = tid + i*256, row = cc >> 3, col8 = (cc & 7) * 8;
            size_t go = (size_t)(kv0+row)*64 + col8;
            size_t gv = (size_t)row*2048 + kv0 + col8;
            *reinterpret_cast<bf16x8*>(&Kh[row*72 + col8]) = *reinterpret_cast<const bf16x8*>(&khb[go]);
            *reinterpret_cast<bf16x8*>(&Vh[row*72 + col8]) = *reinterpret_cast<const bf16x8*>(&vhb[gv]);
        }
        __syncthreads();

        f32x4 s[4] = {};
#pragma unroll
        for (int st = 0; st < 4; st++) {
            const int ro = (st*16 + lane16)*72;
            bf16x8 kh0 = *reinterpret_cast<const bf16x8*>(&Kh[ro + lg*8]);
            bf16x8 kh1 = *reinterpret_cast<const bf16x8*>(&Kh[ro + 32 + lg*8]);
            s[st] = MFMA16(qfr0, kh0, s[st]);
            s[st] = MFMA16(qfr1, kh1, s[st]);
        }
        if (t == qt) {
#pragma unroll
            for (int st = 0; st < 4; st++) {
                int key = kv0 + st*16 + lane16;
#pragma unroll
                for (int r = 0; r < 4; r++) {
                    int qr = q0 + wid*16 + lg*4 + r;
                    if (key > qr) s[st][r] = -1e30f;
                }
            }
        }
        float rmax[4];
#pragma unroll
        for (int r = 0; r < 4; r++)
            rmax[r] = fmaxf(fmaxf(s[0][r], s[1][r]), fmaxf(s[2][r], s[3][r]));
#pragma unroll
        for (int off = 1; off < 16; off <<= 1)
#pragma unroll
            for (int r = 0; r < 4; r++) rmax[r] = fmaxf(rmax[r], __shfl_xor(rmax[r], off));
        float scl[4];
#pragma unroll
        for (int r = 0; r < 4; r++) {
            float mn = fmaxf(mrow[r], rmax[r]);
            scl[r] = exp2f((mrow[r] - mn) * L2E);
            mrow[r] = mn;
        }
        float rs[4] = {0.f, 0.f, 0.f, 0.f};
#pragma unroll
        for (int st = 0; st < 4; st++) {
#pragma unroll
            for (int r = 0; r < 4; r++) {
                float p = exp2f((s[st][r] - mrow[r]) * L2E);
                rs[r] += p;
                Ph[wid*16*72 + (lg*4 + r)*72 + st*16 + lane16] = (bf16_t)p;
            }
        }
#pragma unroll
        for (int off = 1; off < 16; off <<= 1)
#pragma unroll
            for (int r = 0; r < 4; r++) rs[r] += __shfl_xor(rs[r], off);
#pragma unroll
        for (int r = 0; r < 4; r++) lrow[r] = lrow[r]*scl[r] + rs[r];
#pragma unroll
        for (int nf = 0; nf < 4; nf++)
#pragma unroll
            for (int r = 0; r < 4; r++) acco[nf][r] *= scl[r];

        __syncthreads();
#pragma unroll
        for (int ks = 0; ks < 2; ks++) {
            bf16x8 phf = *reinterpret_cast<const bf16x8*>(&Ph[wid*16*72 + lane16*72 + ks*32 + lg*8]);
#pragma unroll
            for (int nf = 0; nf < 4; nf++) {
                bf16x8 vh = *reinterpret_cast<const bf16x8*>(&Vh[(nf*16 + lane16)*72 + ks*32 + lg*8]);
                acco[nf] = MFMA16(phf, vh, acco[nf]);
            }
        }
        __syncthreads();
    }

    const int b = bh >> 4, h = bh & 15;
#pragma unroll
    for (int r = 0; r < 4; r++) {
        float inv = 1.0f / lrow[r];
        int qr = q0 + wid*16 + lg*4 + r;
        size_t base = ((size_t)(b*2048 + qr))*1024 + h*64;
#pragma unroll
        for (int nf = 0; nf < 4; nf++)
            ohi[base + nf*16 + lane16] = (bf16_t)(acco[nf][r] * inv);
    }
}

// ---------------------------------------------------------------------------
extern "C" void kernel_launch(void* const* d_in, const int* in_sizes, int n_in,
                              void* d_out, int out_size, void* d_ws, size_t ws_size,
                              hipStream_t stream)
{
    const float* x  = (const float*)d_in[0];
    const float* Wq = (const float*)d_in[1];
    const float* bq = (const float*)d_in[2];
    const float* Wk = (const float*)d_in[3];
    const float* bk = (const float*)d_in[4];
    const float* Wv = (const float*)d_in[5];
    const float* bv = (const float*)d_in[6];
    const float* Wo = (const float*)d_in[7];
    const float* bo = (const float*)d_in[8];

    char* ws = (char*)d_ws;
    const size_t MB = (size_t)1 << 20;
    bf16_t* xhi    = (bf16_t*)(ws +  0*MB);  // [4096][1024] 8MB
    bf16_t* WThi   = (bf16_t*)(ws +  8*MB);  // [3072][1024] 6MB (Wq|Wk|Wv ^T)
    bf16_t* WoThi  = (bf16_t*)(ws + 14*MB);  // 2MB
    bf16_t* qbuf   = (bf16_t*)(ws + 16*MB);  // [B,H,L,Dh] 8MB
    bf16_t* khibuf = (bf16_t*)(ws + 24*MB);  // 8MB
    bf16_t* vhiT   = (bf16_t*)(ws + 32*MB);  // [B,H,Dh,L] 8MB
    bf16_t* ohibuf = (bf16_t*)(ws + 40*MB);  // [4096][1024] 8MB
    int2*   qwl    = (int2*)  (ws + 48*MB);  // 2MB
    int*    qcnt   = (int*)   (ws + 50*MB);  // 4B

    hipMemsetAsync(qcnt, 0, 4, stream);
    k_conv_x<<<4096, 256, 0, stream>>>(x, xhi);
    dim3 tg(32, 32);
    k_transpose<<<tg, 256, 0, stream>>>(Wq, WThi);
    k_transpose<<<tg, 256, 0, stream>>>(Wk, WThi + (size_t)1024*1024);
    k_transpose<<<tg, 256, 0, stream>>>(Wv, WThi + (size_t)2048*1024);
    k_transpose<<<tg, 256, 0, stream>>>(Wo, WoThi);

    k_gemm3<0><<<768, 256, 0, stream>>>(xhi, WThi, bq, bk, bv,
                                        qbuf, qwl, qcnt, khibuf, vhiT, nullptr);
    k_qfix<<<1024, 256, 0, stream>>>(x, Wq, bq, qwl, qcnt, qbuf);
    k_attn<<<dim3(32, 32), 256, 0, stream>>>(qbuf, khibuf, vhiT, ohibuf);
    k_gemm3<1><<<512, 256, 0, stream>>>(ohibuf, WoThi, bo, nullptr, nullptr,
                                        nullptr, nullptr, nullptr,
                                        nullptr, nullptr, (float*)d_out);
}

// Round 24
// 337.108 us; speedup vs baseline: 2.9238x; 1.1119x over previous
//
#include <hip/hip_runtime.h>
#include <cstddef>
#include <cstdint>
#include <math.h>

typedef __bf16 bf16_t;
typedef __bf16 bf16x8 __attribute__((ext_vector_type(8)));
typedef float  f32x4  __attribute__((ext_vector_type(4)));

#define MFMA16(A,B,C) __builtin_amdgcn_mfma_f32_16x16x32_bf16((A),(B),(C),0,0,0)
#define QFIX_CAP 262144

// B=2, L=2048, D=1024, H=16, Dh=64.
// r24 = r23 + attention load balance: causal pairing — block x handles q-tiles
// {x, 31-x} (uniform 33 tile-iters/block; r23's grid gave every CU 4 same-qt
// blocks -> 128-tile stragglers).  Middle barrier dropped (Ph wave-private).
// Per-element arithmetic unchanged -> absmax invariant 0.0390625.

__device__ __forceinline__ void gload16(const bf16_t* g, bf16_t* l)
{
    auto* lp = reinterpret_cast<__attribute__((address_space(3))) uint32_t*>(
                   reinterpret_cast<uintptr_t>(l));
    const auto* gp = reinterpret_cast<const __attribute__((address_space(1))) uint32_t*>(
                   reinterpret_cast<uintptr_t>(g));
    __builtin_amdgcn_global_load_lds(gp, lp, 16, 0, 0);
}

// ---------------------------------------------------------------------------
__global__ void k_conv_x(const float* __restrict__ x, bf16_t* __restrict__ xhi)
{
    int i = blockIdx.x * blockDim.x + threadIdx.x;
    float4 v = reinterpret_cast<const float4*>(x)[i];
    bf16_t* ph = xhi + 4*(size_t)i;
    ph[0]=(bf16_t)v.x; ph[1]=(bf16_t)v.y; ph[2]=(bf16_t)v.z; ph[3]=(bf16_t)v.w;
}

// W f32 [k][n] (1024x1024) -> T[n][k] bf16
__global__ void k_transpose(const float* __restrict__ W, bf16_t* __restrict__ T)
{
    __shared__ float tile[32][33];
    int t = threadIdx.x, r = t >> 5, c = t & 31;
    int k0 = blockIdx.y * 32, n0 = blockIdx.x * 32;
#pragma unroll
    for (int i = 0; i < 4; i++)
        tile[r + i*8][c] = W[(size_t)(k0 + r + i*8) * 1024 + n0 + c];
    __syncthreads();
#pragma unroll
    for (int i = 0; i < 4; i++) {
        int nr = r + i*8;
        T[(size_t)(n0 + nr) * 1024 + k0 + c] = (bf16_t)tile[c][nr];
    }
}

// ---------------------------------------------------------------------------
// Single-pass bf16 MFMA GEMM, depth-2 prefetch, 3 LDS buffers, XCD-local B.
// MODE 0 (QKV): 128x128 tile, N=3072. Epilogue: Q floor+flag(4e-3) / K / V^T.
// MODE 1 (out-proj): 64x128 tile, N=1024 -> f32 d_out + bo.
template<int MODE>
__launch_bounds__(256)
__global__ void k_gemm3(const bf16_t* __restrict__ A, const bf16_t* __restrict__ Bt,
                        const float* __restrict__ b0, const float* __restrict__ b1,
                        const float* __restrict__ b2,
                        bf16_t* __restrict__ qout, int2* __restrict__ qwl,
                        int* __restrict__ qcnt,
                        bf16_t* __restrict__ kho, bf16_t* __restrict__ vho,
                        float* __restrict__ fout)
{
    constexpr int BM = (MODE == 0) ? 128 : 64;
    __shared__ bf16_t As[3][BM*32]  __attribute__((aligned(16)));
    __shared__ bf16_t Bs[3][128*32] __attribute__((aligned(16)));

    const int bid = blockIdx.x;
    const int xcd = bid & 7;
    const int i   = bid >> 3;
    int n0, m0;
    if constexpr (MODE == 0) {
        n0 = (xcd * 3 + (i % 3)) * 128;   // each XCD owns 3 n-tiles (L2-resident B)
        m0 = (i / 3) * 128;
    } else {
        n0 = xcd * 128;
        m0 = i * 64;
    }

    const int tid = threadIdx.x;
    const int wid = tid >> 6, lane = tid & 63, lane16 = lane & 15, lg = lane >> 4;
    constexpr int WM = (MODE == 0) ? 64 : 32;
    const int wm = (wid >> 1) * WM, wn = (wid & 1) * 64;
    constexpr int MI = (MODE == 0) ? 4 : 2;

    f32x4 acc[MI][4] = {};

    auto STAGE = [&](int buf, int kt) {
        const int k0 = kt * 32;
#pragma unroll
        for (int i2 = 0; i2 < BM/64; i2++) {
            const int c = tid + i2*256;
            const int row = c >> 2, col = (c & 3) * 8;
            gload16(&A[(size_t)(m0 + row) * 1024 + k0 + col], &As[buf][c*8]);
        }
#pragma unroll
        for (int i2 = 0; i2 < 2; i2++) {
            const int c = tid + i2*256;
            const int row = c >> 2, col = (c & 3) * 8;
            gload16(&Bt[(size_t)(n0 + row) * 1024 + k0 + col], &Bs[buf][c*8]);
        }
    };

    STAGE(0, 0);
    STAGE(1, 1);
    for (int kt = 0; kt < 32; ++kt) {
        const int cur = kt % 3;
        if (kt < 31) {
            if constexpr (MODE == 0) { asm volatile("s_waitcnt vmcnt(4)" ::: "memory"); }
            else                     { asm volatile("s_waitcnt vmcnt(3)" ::: "memory"); }
        } else asm volatile("s_waitcnt vmcnt(0)" ::: "memory");
        __builtin_amdgcn_s_barrier();

        bf16x8 a[MI], b[4];
#pragma unroll
        for (int ii = 0; ii < MI; ii++)
            a[ii] = *reinterpret_cast<const bf16x8*>(&As[cur][(wm + ii*16 + lane16)*32 + lg*8]);
#pragma unroll
        for (int j = 0; j < 4; j++)
            b[j] = *reinterpret_cast<const bf16x8*>(&Bs[cur][(wn + j*16 + lane16)*32 + lg*8]);
#pragma unroll
        for (int ii = 0; ii < MI; ii++)
#pragma unroll
            for (int j = 0; j < 4; j++)
                acc[ii][j] = MFMA16(a[ii], b[j], acc[ii][j]);

        if (kt + 2 < 32) STAGE((kt + 2) % 3, kt + 2);
    }

    if constexpr (MODE == 1) {
#pragma unroll
        for (int j = 0; j < 4; j++) {
            const int n = n0 + wn + j*16 + lane16;
#pragma unroll
            for (int ii = 0; ii < MI; ii++)
#pragma unroll
                for (int r = 0; r < 4; r++) {
                    const int m = m0 + wm + ii*16 + lg*4 + r;
                    fout[(size_t)m*1024 + n] = acc[ii][j][r] + b0[n];
                }
        }
    } else if (n0 >= 1024) {
#pragma unroll
        for (int j = 0; j < 4; j++) {
            const int n = n0 + wn + j*16 + lane16;
#pragma unroll
            for (int ii = 0; ii < MI; ii++)
#pragma unroll
                for (int r = 0; r < 4; r++) {
                    const int m = m0 + wm + ii*16 + lg*4 + r;
                    const int bb = m >> 11, l = m & 2047;
                    float v = acc[ii][j][r];
                    if (n < 2048) {
                        const int nk = n - 1024;
                        kho[(((size_t)(bb*16 + (nk>>6)))*2048 + l)*64 + (nk&63)] =
                            (bf16_t)(v + b1[nk]);
                    } else {
                        const int nv = n - 2048;
                        vho[(((size_t)(bb*16 + (nv>>6)))*64 + (nv&63))*2048 + l] =
                            (bf16_t)(v + b2[nv]);
                    }
                }
        }
    } else {
        // Q epilogue: floors + wave-aggregated flag append (1 atomic/wave)
        int cnt = 0;
#pragma unroll
        for (int j = 0; j < 4; j++) {
            const int n = n0 + wn + j*16 + lane16;
            const float bias = b0[n];
#pragma unroll
            for (int ii = 0; ii < MI; ii++)
#pragma unroll
                for (int r = 0; r < 4; r++) {
                    const int m = m0 + wm + ii*16 + lg*4 + r;
                    const int bb = m >> 11, l = m & 2047;
                    float t  = (acc[ii][j][r] + bias) * 0.125f;
                    float fl = floorf(t);
                    float fr = t - fl;
                    cnt += (fr < 4e-3f || fr > 0.996f) ? 1 : 0;
                    qout[(((size_t)(bb*16 + (n>>6)))*2048 + l)*64 + (n&63)] = (bf16_t)fl;
                }
        }
        int pre = cnt;
#pragma unroll
        for (int off = 1; off < 64; off <<= 1) {
            int t2 = __shfl_up(pre, off);
            if (lane >= off) pre += t2;
        }
        int total = __shfl(pre, 63);
        int base = 0;
        if (lane == 63 && total > 0) base = atomicAdd(qcnt, total);
        base = __shfl(base, 63);
        int idx = base + pre - cnt;
#pragma unroll
        for (int j = 0; j < 4; j++) {
            const int n = n0 + wn + j*16 + lane16;
            const float bias = b0[n];
#pragma unroll
            for (int ii = 0; ii < MI; ii++)
#pragma unroll
                for (int r = 0; r < 4; r++) {
                    const int m = m0 + wm + ii*16 + lg*4 + r;
                    float t  = (acc[ii][j][r] + bias) * 0.125f;
                    float fr = t - floorf(t);
                    if (fr < 4e-3f || fr > 0.996f) {
                        if (idx < QFIX_CAP) qwl[idx] = make_int2(m, n);
                        idx++;
                    }
                }
        }
    }
}

// ---------------------------------------------------------------------------
// Exact fixup (r11-verified arithmetic, bit-identical): recompute flagged q.
__launch_bounds__(256)
__global__ void k_qfix(const float* __restrict__ x, const float* __restrict__ Wq,
                       const float* __restrict__ bq, const int2* __restrict__ wl,
                       const int* __restrict__ count, bf16_t* __restrict__ qout)
{
    int i = blockIdx.x * 256 + threadIdx.x;
    int cnt = *count; if (cnt > QFIX_CAP) cnt = QFIX_CAP;
    if (i >= cnt) return;
    const int m = wl[i].x, n = wl[i].y;
    const float* xr = x + (size_t)m * 1024;
    float acc = 0.0f;
#pragma unroll 1
    for (int blk = 0; blk < 2; blk++) {
        float r = 0.0f;
        const int d0 = blk * 512;
#pragma unroll 8
        for (int d = d0; d < d0 + 512; d++)
            r = fmaf(xr[d], Wq[(size_t)d * 1024 + n], r);
        acc = __fadd_rn(acc, r);
    }
    float q = floorf(__fmul_rn(__fadd_rn(acc, bq[n]), 0.125f));
    qout[(((size_t)((m>>11)*16 + (n>>6)))*2048 + (m&2047))*64 + (n&63)] = (bf16_t)q;
}

// ---------------------------------------------------------------------------
// Flash attention, bf16 K/V/P. grid (16, B*H); block x handles q-tiles
// {x, 31-x} sequentially (uniform 33 tile-iters). 4 waves x 16 q-rows.
__launch_bounds__(256)
__global__ void k_attn(const bf16_t* __restrict__ qf,
                       const bf16_t* __restrict__ khi,
                       const bf16_t* __restrict__ vhiT,
                       bf16_t* __restrict__ ohi)
{
    __shared__ bf16_t Kh[64*72] __attribute__((aligned(16)));
    __shared__ bf16_t Vh[64*72] __attribute__((aligned(16)));
    __shared__ bf16_t Ph[4*16*72] __attribute__((aligned(16)));
    const int tid = threadIdx.x, wid = tid >> 6, lane = tid & 63;
    const int lane16 = lane & 15, lg = lane >> 4;
    const int bx = blockIdx.x, bh = blockIdx.y;
    const bf16_t* qb  = qf   + (size_t)bh * 2048 * 64;
    const bf16_t* khb = khi  + (size_t)bh * 2048 * 64;
    const bf16_t* vhb = vhiT + (size_t)bh * 64 * 2048;
    const int b = bh >> 4, h = bh & 15;
    const float L2E = 1.44269504088896f;

#pragma unroll 1
    for (int pass = 0; pass < 2; pass++) {
        const int qt = pass ? (31 - bx) : bx;
        const int q0 = qt * 64;
        const int qrow16 = q0 + wid*16 + lane16;

        bf16x8 qfr0 = *reinterpret_cast<const bf16x8*>(&qb[(size_t)qrow16*64 + lg*8]);
        bf16x8 qfr1 = *reinterpret_cast<const bf16x8*>(&qb[(size_t)qrow16*64 + 32 + lg*8]);

        f32x4 acco[4] = {};
        float mrow[4] = {-1e30f, -1e30f, -1e30f, -1e30f};
        float lrow[4] = {0.f, 0.f, 0.f, 0.f};

        for (int t = 0; t <= qt; t++) {
            const int kv0 = t * 64;
#pragma unroll
            for (int i = 0; i < 2; i++) {
                int cc = tid + i*256, row = cc >> 3, col8 = (cc & 7) * 8;
                size_t go = (size_t)(kv0+row)*64 + col8;
                size_t gv = (size_t)row*2048 + kv0 + col8;
                *reinterpret_cast<bf16x8*>(&Kh[row*72 + col8]) = *reinterpret_cast<const bf16x8*>(&khb[go]);
                *reinterpret_cast<bf16x8*>(&Vh[row*72 + col8]) = *reinterpret_cast<const bf16x8*>(&vhb[gv]);
            }
            __syncthreads();

            f32x4 s[4] = {};
#pragma unroll
            for (int st = 0; st < 4; st++) {
                const int ro = (st*16 + lane16)*72;
                bf16x8 kh0 = *reinterpret_cast<const bf16x8*>(&Kh[ro + lg*8]);
                bf16x8 kh1 = *reinterpret_cast<const bf16x8*>(&Kh[ro + 32 + lg*8]);
                s[st] = MFMA16(qfr0, kh0, s[st]);
                s[st] = MFMA16(qfr1, kh1, s[st]);
            }
            if (t == qt) {
#pragma unroll
                for (int st = 0; st < 4; st++) {
                    int key = kv0 + st*16 + lane16;
#pragma unroll
                    for (int r = 0; r < 4; r++) {
                        int qr = q0 + wid*16 + lg*4 + r;
                        if (key > qr) s[st][r] = -1e30f;
                    }
                }
            }
            float rmax[4];
#pragma unroll
            for (int r = 0; r < 4; r++)
                rmax[r] = fmaxf(fmaxf(s[0][r], s[1][r]), fmaxf(s[2][r], s[3][r]));
#pragma unroll
            for (int off = 1; off < 16; off <<= 1)
#pragma unroll
                for (int r = 0; r < 4; r++) rmax[r] = fmaxf(rmax[r], __shfl_xor(rmax[r], off));
            float scl[4];
#pragma unroll
            for (int r = 0; r < 4; r++) {
                float mn = fmaxf(mrow[r], rmax[r]);
                scl[r] = exp2f((mrow[r] - mn) * L2E);
                mrow[r] = mn;
            }
            float rs[4] = {0.f, 0.f, 0.f, 0.f};
#pragma unroll
            for (int st = 0; st < 4; st++) {
#pragma unroll
                for (int r = 0; r < 4; r++) {
                    float p = exp2f((s[st][r] - mrow[r]) * L2E);
                    rs[r] += p;
                    Ph[wid*16*72 + (lg*4 + r)*72 + st*16 + lane16] = (bf16_t)p;
                }
            }
#pragma unroll
            for (int off = 1; off < 16; off <<= 1)
#pragma unroll
                for (int r = 0; r < 4; r++) rs[r] += __shfl_xor(rs[r], off);
#pragma unroll
            for (int r = 0; r < 4; r++) lrow[r] = lrow[r]*scl[r] + rs[r];
#pragma unroll
            for (int nf = 0; nf < 4; nf++)
#pragma unroll
                for (int r = 0; r < 4; r++) acco[nf][r] *= scl[r];

            // Ph is wave-private (written and read by the same wave) — no barrier
#pragma unroll
            for (int ks = 0; ks < 2; ks++) {
                bf16x8 phf = *reinterpret_cast<const bf16x8*>(&Ph[wid*16*72 + lane16*72 + ks*32 + lg*8]);
#pragma unroll
                for (int nf = 0; nf < 4; nf++) {
                    bf16x8 vh = *reinterpret_cast<const bf16x8*>(&Vh[(nf*16 + lane16)*72 + ks*32 + lg*8]);
                    acco[nf] = MFMA16(phf, vh, acco[nf]);
                }
            }
            __syncthreads();   // Kh/Vh read-done before next staging
        }

#pragma unroll
        for (int r = 0; r < 4; r++) {
            float inv = 1.0f / lrow[r];
            int qr = q0 + wid*16 + lg*4 + r;
            size_t base = ((size_t)(b*2048 + qr))*1024 + h*64;
#pragma unroll
            for (int nf = 0; nf < 4; nf++)
                ohi[base + nf*16 + lane16] = (bf16_t)(acco[nf][r] * inv);
        }
    }
}

// ---------------------------------------------------------------------------
extern "C" void kernel_launch(void* const* d_in, const int* in_sizes, int n_in,
                              void* d_out, int out_size, void* d_ws, size_t ws_size,
                              hipStream_t stream)
{
    const float* x  = (const float*)d_in[0];
    const float* Wq = (const float*)d_in[1];
    const float* bq = (const float*)d_in[2];
    const float* Wk = (const float*)d_in[3];
    const float* bk = (const float*)d_in[4];
    const float* Wv = (const float*)d_in[5];
    const float* bv = (const float*)d_in[6];
    const float* Wo = (const float*)d_in[7];
    const float* bo = (const float*)d_in[8];

    char* ws = (char*)d_ws;
    const size_t MB = (size_t)1 << 20;
    bf16_t* xhi    = (bf16_t*)(ws +  0*MB);  // [4096][1024] 8MB
    bf16_t* WThi   = (bf16_t*)(ws +  8*MB);  // [3072][1024] 6MB (Wq|Wk|Wv ^T)
    bf16_t* WoThi  = (bf16_t*)(ws + 14*MB);  // 2MB
    bf16_t* qbuf   = (bf16_t*)(ws + 16*MB);  // [B,H,L,Dh] 8MB
    bf16_t* khibuf = (bf16_t*)(ws + 24*MB);  // 8MB
    bf16_t* vhiT   = (bf16_t*)(ws + 32*MB);  // [B,H,Dh,L] 8MB
    bf16_t* ohibuf = (bf16_t*)(ws + 40*MB);  // [4096][1024] 8MB
    int2*   qwl    = (int2*)  (ws + 48*MB);  // 2MB
    int*    qcnt   = (int*)   (ws + 50*MB);  // 4B

    hipMemsetAsync(qcnt, 0, 4, stream);
    k_conv_x<<<4096, 256, 0, stream>>>(x, xhi);
    dim3 tg(32, 32);
    k_transpose<<<tg, 256, 0, stream>>>(Wq, WThi);
    k_transpose<<<tg, 256, 0, stream>>>(Wk, WThi + (size_t)1024*1024);
    k_transpose<<<tg, 256, 0, stream>>>(Wv, WThi + (size_t)2048*1024);
    k_transpose<<<tg, 256, 0, stream>>>(Wo, WoThi);

    k_gemm3<0><<<768, 256, 0, stream>>>(xhi, WThi, bq, bk, bv,
                                        qbuf, qwl, qcnt, khibuf, vhiT, nullptr);
    k_qfix<<<1024, 256, 0, stream>>>(x, Wq, bq, qwl, qcnt, qbuf);
    k_attn<<<dim3(16, 32), 256, 0, stream>>>(qbuf, khibuf, vhiT, ohibuf);
    k_gemm3<1><<<512, 256, 0, stream>>>(ohibuf, WoThi, bo, nullptr, nullptr,
                                        nullptr, nullptr, nullptr,
                                        nullptr, nullptr, (float*)d_out);
}

// Round 25
// 336.496 us; speedup vs baseline: 2.9292x; 1.0018x over previous
//
#include <hip/hip_runtime.h>
#include <cstddef>
#include <cstdint>
#include <math.h>

typedef __bf16 bf16_t;
typedef __bf16 bf16x8 __attribute__((ext_vector_type(8)));
typedef float  f32x4  __attribute__((ext_vector_type(4)));

#define MFMA16(A,B,C) __builtin_amdgcn_mfma_f32_16x16x32_bf16((A),(B),(C),0,0,0)
#define QFIX_CAP 262144

// B=2, L=2048, D=1024, H=16, Dh=64.
// r25 = r24 + fast qfix: Wq transposed to f32 [n][k] so each fixup thread
// reads contiguous x-row + WqT-row via float4; the two KC=512 chains run as
// independent r0/r1 registers (2x ILP).  Chain order within each block
// unchanged -> q bit-identical -> absmax invariant 0.0390625.

__device__ __forceinline__ void gload16(const bf16_t* g, bf16_t* l)
{
    auto* lp = reinterpret_cast<__attribute__((address_space(3))) uint32_t*>(
                   reinterpret_cast<uintptr_t>(l));
    const auto* gp = reinterpret_cast<const __attribute__((address_space(1))) uint32_t*>(
                   reinterpret_cast<uintptr_t>(g));
    __builtin_amdgcn_global_load_lds(gp, lp, 16, 0, 0);
}

// ---------------------------------------------------------------------------
__global__ void k_conv_x(const float* __restrict__ x, bf16_t* __restrict__ xhi)
{
    int i = blockIdx.x * blockDim.x + threadIdx.x;
    float4 v = reinterpret_cast<const float4*>(x)[i];
    bf16_t* ph = xhi + 4*(size_t)i;
    ph[0]=(bf16_t)v.x; ph[1]=(bf16_t)v.y; ph[2]=(bf16_t)v.z; ph[3]=(bf16_t)v.w;
}

// W f32 [k][n] (1024x1024) -> T[n][k] bf16
__global__ void k_transpose(const float* __restrict__ W, bf16_t* __restrict__ T)
{
    __shared__ float tile[32][33];
    int t = threadIdx.x, r = t >> 5, c = t & 31;
    int k0 = blockIdx.y * 32, n0 = blockIdx.x * 32;
#pragma unroll
    for (int i = 0; i < 4; i++)
        tile[r + i*8][c] = W[(size_t)(k0 + r + i*8) * 1024 + n0 + c];
    __syncthreads();
#pragma unroll
    for (int i = 0; i < 4; i++) {
        int nr = r + i*8;
        T[(size_t)(n0 + nr) * 1024 + k0 + c] = (bf16_t)tile[c][nr];
    }
}

// W f32 [k][n] -> T f32 [n][k]  (for the exact qfix row reads)
__global__ void k_transpose_f32(const float* __restrict__ W, float* __restrict__ T)
{
    __shared__ float tile[32][33];
    int t = threadIdx.x, r = t >> 5, c = t & 31;
    int k0 = blockIdx.y * 32, n0 = blockIdx.x * 32;
#pragma unroll
    for (int i = 0; i < 4; i++)
        tile[r + i*8][c] = W[(size_t)(k0 + r + i*8) * 1024 + n0 + c];
    __syncthreads();
#pragma unroll
    for (int i = 0; i < 4; i++) {
        int nr = r + i*8;
        T[(size_t)(n0 + nr) * 1024 + k0 + c] = tile[c][nr];
    }
}

// ---------------------------------------------------------------------------
// Single-pass bf16 MFMA GEMM, depth-2 prefetch, 3 LDS buffers, XCD-local B.
// MODE 0 (QKV): 128x128 tile, N=3072. Epilogue: Q floor+flag(4e-3) / K / V^T.
// MODE 1 (out-proj): 64x128 tile, N=1024 -> f32 d_out + bo.
template<int MODE>
__launch_bounds__(256)
__global__ void k_gemm3(const bf16_t* __restrict__ A, const bf16_t* __restrict__ Bt,
                        const float* __restrict__ b0, const float* __restrict__ b1,
                        const float* __restrict__ b2,
                        bf16_t* __restrict__ qout, int2* __restrict__ qwl,
                        int* __restrict__ qcnt,
                        bf16_t* __restrict__ kho, bf16_t* __restrict__ vho,
                        float* __restrict__ fout)
{
    constexpr int BM = (MODE == 0) ? 128 : 64;
    __shared__ bf16_t As[3][BM*32]  __attribute__((aligned(16)));
    __shared__ bf16_t Bs[3][128*32] __attribute__((aligned(16)));

    const int bid = blockIdx.x;
    const int xcd = bid & 7;
    const int i   = bid >> 3;
    int n0, m0;
    if constexpr (MODE == 0) {
        n0 = (xcd * 3 + (i % 3)) * 128;   // each XCD owns 3 n-tiles (L2-resident B)
        m0 = (i / 3) * 128;
    } else {
        n0 = xcd * 128;
        m0 = i * 64;
    }

    const int tid = threadIdx.x;
    const int wid = tid >> 6, lane = tid & 63, lane16 = lane & 15, lg = lane >> 4;
    constexpr int WM = (MODE == 0) ? 64 : 32;
    const int wm = (wid >> 1) * WM, wn = (wid & 1) * 64;
    constexpr int MI = (MODE == 0) ? 4 : 2;

    f32x4 acc[MI][4] = {};

    auto STAGE = [&](int buf, int kt) {
        const int k0 = kt * 32;
#pragma unroll
        for (int i2 = 0; i2 < BM/64; i2++) {
            const int c = tid + i2*256;
            const int row = c >> 2, col = (c & 3) * 8;
            gload16(&A[(size_t)(m0 + row) * 1024 + k0 + col], &As[buf][c*8]);
        }
#pragma unroll
        for (int i2 = 0; i2 < 2; i2++) {
            const int c = tid + i2*256;
            const int row = c >> 2, col = (c & 3) * 8;
            gload16(&Bt[(size_t)(n0 + row) * 1024 + k0 + col], &Bs[buf][c*8]);
        }
    };

    STAGE(0, 0);
    STAGE(1, 1);
    for (int kt = 0; kt < 32; ++kt) {
        const int cur = kt % 3;
        if (kt < 31) {
            if constexpr (MODE == 0) { asm volatile("s_waitcnt vmcnt(4)" ::: "memory"); }
            else                     { asm volatile("s_waitcnt vmcnt(3)" ::: "memory"); }
        } else asm volatile("s_waitcnt vmcnt(0)" ::: "memory");
        __builtin_amdgcn_s_barrier();

        bf16x8 a[MI], b[4];
#pragma unroll
        for (int ii = 0; ii < MI; ii++)
            a[ii] = *reinterpret_cast<const bf16x8*>(&As[cur][(wm + ii*16 + lane16)*32 + lg*8]);
#pragma unroll
        for (int j = 0; j < 4; j++)
            b[j] = *reinterpret_cast<const bf16x8*>(&Bs[cur][(wn + j*16 + lane16)*32 + lg*8]);
#pragma unroll
        for (int ii = 0; ii < MI; ii++)
#pragma unroll
            for (int j = 0; j < 4; j++)
                acc[ii][j] = MFMA16(a[ii], b[j], acc[ii][j]);

        if (kt + 2 < 32) STAGE((kt + 2) % 3, kt + 2);
    }

    if constexpr (MODE == 1) {
#pragma unroll
        for (int j = 0; j < 4; j++) {
            const int n = n0 + wn + j*16 + lane16;
#pragma unroll
            for (int ii = 0; ii < MI; ii++)
#pragma unroll
                for (int r = 0; r < 4; r++) {
                    const int m = m0 + wm + ii*16 + lg*4 + r;
                    fout[(size_t)m*1024 + n] = acc[ii][j][r] + b0[n];
                }
        }
    } else if (n0 >= 1024) {
#pragma unroll
        for (int j = 0; j < 4; j++) {
            const int n = n0 + wn + j*16 + lane16;
#pragma unroll
            for (int ii = 0; ii < MI; ii++)
#pragma unroll
                for (int r = 0; r < 4; r++) {
                    const int m = m0 + wm + ii*16 + lg*4 + r;
                    const int bb = m >> 11, l = m & 2047;
                    float v = acc[ii][j][r];
                    if (n < 2048) {
                        const int nk = n - 1024;
                        kho[(((size_t)(bb*16 + (nk>>6)))*2048 + l)*64 + (nk&63)] =
                            (bf16_t)(v + b1[nk]);
                    } else {
                        const int nv = n - 2048;
                        vho[(((size_t)(bb*16 + (nv>>6)))*64 + (nv&63))*2048 + l] =
                            (bf16_t)(v + b2[nv]);
                    }
                }
        }
    } else {
        // Q epilogue: floors + wave-aggregated flag append (1 atomic/wave)
        int cnt = 0;
#pragma unroll
        for (int j = 0; j < 4; j++) {
            const int n = n0 + wn + j*16 + lane16;
            const float bias = b0[n];
#pragma unroll
            for (int ii = 0; ii < MI; ii++)
#pragma unroll
                for (int r = 0; r < 4; r++) {
                    const int m = m0 + wm + ii*16 + lg*4 + r;
                    const int bb = m >> 11, l = m & 2047;
                    float t  = (acc[ii][j][r] + bias) * 0.125f;
                    float fl = floorf(t);
                    float fr = t - fl;
                    cnt += (fr < 4e-3f || fr > 0.996f) ? 1 : 0;
                    qout[(((size_t)(bb*16 + (n>>6)))*2048 + l)*64 + (n&63)] = (bf16_t)fl;
                }
        }
        int pre = cnt;
#pragma unroll
        for (int off = 1; off < 64; off <<= 1) {
            int t2 = __shfl_up(pre, off);
            if (lane >= off) pre += t2;
        }
        int total = __shfl(pre, 63);
        int base = 0;
        if (lane == 63 && total > 0) base = atomicAdd(qcnt, total);
        base = __shfl(base, 63);
        int idx = base + pre - cnt;
#pragma unroll
        for (int j = 0; j < 4; j++) {
            const int n = n0 + wn + j*16 + lane16;
            const float bias = b0[n];
#pragma unroll
            for (int ii = 0; ii < MI; ii++)
#pragma unroll
                for (int r = 0; r < 4; r++) {
                    const int m = m0 + wm + ii*16 + lg*4 + r;
                    float t  = (acc[ii][j][r] + bias) * 0.125f;
                    float fr = t - floorf(t);
                    if (fr < 4e-3f || fr > 0.996f) {
                        if (idx < QFIX_CAP) qwl[idx] = make_int2(m, n);
                        idx++;
                    }
                }
        }
    }
}

// ---------------------------------------------------------------------------
// Exact fixup: WqT f32 [n][k] rows, float4 reads, independent KC=512 chains.
// Chain order within each block identical to r11 -> bit-identical q.
__launch_bounds__(256)
__global__ void k_qfix(const float* __restrict__ x, const float* __restrict__ WqT,
                       const float* __restrict__ bq, const int2* __restrict__ wl,
                       const int* __restrict__ count, bf16_t* __restrict__ qout)
{
    int i = blockIdx.x * 256 + threadIdx.x;
    int cnt = *count; if (cnt > QFIX_CAP) cnt = QFIX_CAP;
    if (i >= cnt) return;
    const int m = wl[i].x, n = wl[i].y;
    const float4* xr = reinterpret_cast<const float4*>(x   + (size_t)m * 1024);
    const float4* wr = reinterpret_cast<const float4*>(WqT + (size_t)n * 1024);
    float r0 = 0.0f, r1 = 0.0f;
#pragma unroll 8
    for (int d4 = 0; d4 < 128; d4++) {
        float4 x0 = xr[d4],       w0 = wr[d4];
        float4 x1 = xr[d4 + 128], w1 = wr[d4 + 128];
        r0 = fmaf(x0.x, w0.x, r0);  r1 = fmaf(x1.x, w1.x, r1);
        r0 = fmaf(x0.y, w0.y, r0);  r1 = fmaf(x1.y, w1.y, r1);
        r0 = fmaf(x0.z, w0.z, r0);  r1 = fmaf(x1.z, w1.z, r1);
        r0 = fmaf(x0.w, w0.w, r0);  r1 = fmaf(x1.w, w1.w, r1);
    }
    float acc = __fadd_rn(r0, r1);      // == ((0+r0)+r1) of the r11 chain
    float q = floorf(__fmul_rn(__fadd_rn(acc, bq[n]), 0.125f));
    qout[(((size_t)((m>>11)*16 + (n>>6)))*2048 + (m&2047))*64 + (n&63)] = (bf16_t)q;
}

// ---------------------------------------------------------------------------
// Flash attention, bf16 K/V/P. grid (16, B*H); block x handles q-tiles
// {x, 31-x} sequentially (uniform 33 tile-iters). 4 waves x 16 q-rows.
__launch_bounds__(256)
__global__ void k_attn(const bf16_t* __restrict__ qf,
                       const bf16_t* __restrict__ khi,
                       const bf16_t* __restrict__ vhiT,
                       bf16_t* __restrict__ ohi)
{
    __shared__ bf16_t Kh[64*72] __attribute__((aligned(16)));
    __shared__ bf16_t Vh[64*72] __attribute__((aligned(16)));
    __shared__ bf16_t Ph[4*16*72] __attribute__((aligned(16)));
    const int tid = threadIdx.x, wid = tid >> 6, lane = tid & 63;
    const int lane16 = lane & 15, lg = lane >> 4;
    const int bx = blockIdx.x, bh = blockIdx.y;
    const bf16_t* qb  = qf   + (size_t)bh * 2048 * 64;
    const bf16_t* khb = khi  + (size_t)bh * 2048 * 64;
    const bf16_t* vhb = vhiT + (size_t)bh * 64 * 2048;
    const int b = bh >> 4, h = bh & 15;
    const float L2E = 1.44269504088896f;

#pragma unroll 1
    for (int pass = 0; pass < 2; pass++) {
        const int qt = pass ? (31 - bx) : bx;
        const int q0 = qt * 64;
        const int qrow16 = q0 + wid*16 + lane16;

        bf16x8 qfr0 = *reinterpret_cast<const bf16x8*>(&qb[(size_t)qrow16*64 + lg*8]);
        bf16x8 qfr1 = *reinterpret_cast<const bf16x8*>(&qb[(size_t)qrow16*64 + 32 + lg*8]);

        f32x4 acco[4] = {};
        float mrow[4] = {-1e30f, -1e30f, -1e30f, -1e30f};
        float lrow[4] = {0.f, 0.f, 0.f, 0.f};

        for (int t = 0; t <= qt; t++) {
            const int kv0 = t * 64;
#pragma unroll
            for (int i = 0; i < 2; i++) {
                int cc = tid + i*256, row = cc >> 3, col8 = (cc & 7) * 8;
                size_t go = (size_t)(kv0+row)*64 + col8;
                size_t gv = (size_t)row*2048 + kv0 + col8;
                *reinterpret_cast<bf16x8*>(&Kh[row*72 + col8]) = *reinterpret_cast<const bf16x8*>(&khb[go]);
                *reinterpret_cast<bf16x8*>(&Vh[row*72 + col8]) = *reinterpret_cast<const bf16x8*>(&vhb[gv]);
            }
            __syncthreads();

            f32x4 s[4] = {};
#pragma unroll
            for (int st = 0; st < 4; st++) {
                const int ro = (st*16 + lane16)*72;
                bf16x8 kh0 = *reinterpret_cast<const bf16x8*>(&Kh[ro + lg*8]);
                bf16x8 kh1 = *reinterpret_cast<const bf16x8*>(&Kh[ro + 32 + lg*8]);
                s[st] = MFMA16(qfr0, kh0, s[st]);
                s[st] = MFMA16(qfr1, kh1, s[st]);
            }
            if (t == qt) {
#pragma unroll
                for (int st = 0; st < 4; st++) {
                    int key = kv0 + st*16 + lane16;
#pragma unroll
                    for (int r = 0; r < 4; r++) {
                        int qr = q0 + wid*16 + lg*4 + r;
                        if (key > qr) s[st][r] = -1e30f;
                    }
                }
            }
            float rmax[4];
#pragma unroll
            for (int r = 0; r < 4; r++)
                rmax[r] = fmaxf(fmaxf(s[0][r], s[1][r]), fmaxf(s[2][r], s[3][r]));
#pragma unroll
            for (int off = 1; off < 16; off <<= 1)
#pragma unroll
                for (int r = 0; r < 4; r++) rmax[r] = fmaxf(rmax[r], __shfl_xor(rmax[r], off));
            float scl[4];
#pragma unroll
            for (int r = 0; r < 4; r++) {
                float mn = fmaxf(mrow[r], rmax[r]);
                scl[r] = exp2f((mrow[r] - mn) * L2E);
                mrow[r] = mn;
            }
            float rs[4] = {0.f, 0.f, 0.f, 0.f};
#pragma unroll
            for (int st = 0; st < 4; st++) {
#pragma unroll
                for (int r = 0; r < 4; r++) {
                    float p = exp2f((s[st][r] - mrow[r]) * L2E);
                    rs[r] += p;
                    Ph[wid*16*72 + (lg*4 + r)*72 + st*16 + lane16] = (bf16_t)p;
                }
            }
#pragma unroll
            for (int off = 1; off < 16; off <<= 1)
#pragma unroll
                for (int r = 0; r < 4; r++) rs[r] += __shfl_xor(rs[r], off);
#pragma unroll
            for (int r = 0; r < 4; r++) lrow[r] = lrow[r]*scl[r] + rs[r];
#pragma unroll
            for (int nf = 0; nf < 4; nf++)
#pragma unroll
                for (int r = 0; r < 4; r++) acco[nf][r] *= scl[r];

            // Ph wave-private — no barrier needed before PV
#pragma unroll
            for (int ks = 0; ks < 2; ks++) {
                bf16x8 phf = *reinterpret_cast<const bf16x8*>(&Ph[wid*16*72 + lane16*72 + ks*32 + lg*8]);
#pragma unroll
                for (int nf = 0; nf < 4; nf++) {
                    bf16x8 vh = *reinterpret_cast<const bf16x8*>(&Vh[(nf*16 + lane16)*72 + ks*32 + lg*8]);
                    acco[nf] = MFMA16(phf, vh, acco[nf]);
                }
            }
            __syncthreads();   // Kh/Vh read-done before next staging
        }

#pragma unroll
        for (int r = 0; r < 4; r++) {
            float inv = 1.0f / lrow[r];
            int qr = q0 + wid*16 + lg*4 + r;
            size_t base = ((size_t)(b*2048 + qr))*1024 + h*64;
#pragma unroll
            for (int nf = 0; nf < 4; nf++)
                ohi[base + nf*16 + lane16] = (bf16_t)(acco[nf][r] * inv);
        }
    }
}

// ---------------------------------------------------------------------------
extern "C" void kernel_launch(void* const* d_in, const int* in_sizes, int n_in,
                              void* d_out, int out_size, void* d_ws, size_t ws_size,
                              hipStream_t stream)
{
    const float* x  = (const float*)d_in[0];
    const float* Wq = (const float*)d_in[1];
    const float* bq = (const float*)d_in[2];
    const float* Wk = (const float*)d_in[3];
    const float* bk = (const float*)d_in[4];
    const float* Wv = (const float*)d_in[5];
    const float* bv = (const float*)d_in[6];
    const float* Wo = (const float*)d_in[7];
    const float* bo = (const float*)d_in[8];

    char* ws = (char*)d_ws;
    const size_t MB = (size_t)1 << 20;
    bf16_t* xhi    = (bf16_t*)(ws +  0*MB);  // [4096][1024] 8MB
    bf16_t* WThi   = (bf16_t*)(ws +  8*MB);  // [3072][1024] 6MB (Wq|Wk|Wv ^T)
    bf16_t* WoThi  = (bf16_t*)(ws + 14*MB);  // 2MB
    bf16_t* qbuf   = (bf16_t*)(ws + 16*MB);  // [B,H,L,Dh] 8MB
    bf16_t* khibuf = (bf16_t*)(ws + 24*MB);  // 8MB
    bf16_t* vhiT   = (bf16_t*)(ws + 32*MB);  // [B,H,Dh,L] 8MB
    bf16_t* ohibuf = (bf16_t*)(ws + 40*MB);  // [4096][1024] 8MB
    int2*   qwl    = (int2*)  (ws + 48*MB);  // 2MB
    int*    qcnt   = (int*)   (ws + 50*MB);  // 4B
    float*  WqTf   = (float*) (ws + 52*MB);  // [1024][1024] f32 4MB (qfix rows)

    hipMemsetAsync(qcnt, 0, 4, stream);
    k_conv_x<<<4096, 256, 0, stream>>>(x, xhi);
    dim3 tg(32, 32);
    k_transpose<<<tg, 256, 0, stream>>>(Wq, WThi);
    k_transpose<<<tg, 256, 0, stream>>>(Wk, WThi + (size_t)1024*1024);
    k_transpose<<<tg, 256, 0, stream>>>(Wv, WThi + (size_t)2048*1024);
    k_transpose<<<tg, 256, 0, stream>>>(Wo, WoThi);
    k_transpose_f32<<<tg, 256, 0, stream>>>(Wq, WqTf);

    k_gemm3<0><<<768, 256, 0, stream>>>(xhi, WThi, bq, bk, bv,
                                        qbuf, qwl, qcnt, khibuf, vhiT, nullptr);
    k_qfix<<<1024, 256, 0, stream>>>(x, WqTf, bq, qwl, qcnt, qbuf);
    k_attn<<<dim3(16, 32), 256, 0, stream>>>(qbuf, khibuf, vhiT, ohibuf);
    k_gemm3<1><<<512, 256, 0, stream>>>(ohibuf, WoThi, bo, nullptr, nullptr,
                                        nullptr, nullptr, nullptr,
                                        nullptr, nullptr, (float*)d_out);
}